// Round 1
// baseline (2203.236 us; speedup 1.0000x reference)
//
#include <hip/hip_runtime.h>
#include <math.h>

#define N_PATHS 50000
#define N_LINKS 10000
#define LPATH   8
#define DEG     40
#define DIM     64
#define G3      192
#define ITERS   8

__device__ __forceinline__ float fsigmoid(float x){ return 1.0f/(1.0f + __expf(-x)); }
__device__ __forceinline__ float ftanh(float x){ return 1.0f - 2.0f/(__expf(2.0f*x) + 1.0f); }

// ---------------- path embedding: thread=(path_local, j), 4 paths/block ----------------
__global__ __launch_bounds__(256) void path_embed(
    const float* __restrict__ ft, const float* __restrict__ fp, const float* __restrict__ fps,
    const float* __restrict__ w1, const float* __restrict__ b1,
    const float* __restrict__ w2, const float* __restrict__ b2,
    float* __restrict__ path_state)
{
  __shared__ float h1[4][DIM];
  int j  = threadIdx.x & 63;
  int pl = threadIdx.x >> 6;
  int p  = blockIdx.x*4 + pl;
  float x0 = ft[p]*1e-4f, x1 = fp[p]*1e-3f, x2 = fps[p]*1e-3f;
  float h = b1[j] + x0*w1[0*DIM+j] + x1*w1[1*DIM+j] + x2*w1[2*DIM+j];
  h1[pl][j] = fmaxf(h, 0.f);
  __syncthreads();
  float acc = b2[j];
  #pragma unroll 8
  for (int k=0;k<DIM;k++) acc = fmaf(h1[pl][k], w2[k*DIM+j], acc);
  path_state[p*DIM+j] = fmaxf(acc, 0.f);
}

// ---------------- link embedding (incl. load computation), wave = 1 link ----------------
__global__ __launch_bounds__(256) void link_embed(
    const float* __restrict__ ft, const float* __restrict__ cap, const int* __restrict__ ptl,
    const float* __restrict__ w1, const float* __restrict__ b1,
    const float* __restrict__ w2, const float* __restrict__ b2,
    float* __restrict__ link_state)
{
  __shared__ float h1[4][DIM];
  int j  = threadIdx.x & 63;
  int wl = threadIdx.x >> 6;
  int l  = blockIdx.x*4 + wl;
  float s = 0.f;
  if (j < DEG) s = ft[ptl[(l*DEG + j)*2 + 0]];
  #pragma unroll
  for (int off=32; off; off>>=1) s += __shfl_down(s, off);
  float load = __shfl(s, 0) / (cap[l]*1e9f);
  float x0 = cap[l]*1e-5f;
  float h = b1[j] + x0*w1[0*DIM+j] + load*w1[1*DIM+j];
  h1[wl][j] = fmaxf(h, 0.f);
  __syncthreads();
  float acc = b2[j];
  #pragma unroll 8
  for (int k=0;k<DIM;k++) acc = fmaf(h1[wl][k], w2[k*DIM+j], acc);
  link_state[l*DIM+j] = fmaxf(acc, 0.f);
}

// ---------------- LX = link_state @ pg_wx + pg_bx  (10000 x 192), 4 links/block ----------------
__global__ __launch_bounds__(192) void compute_lx(
    const float* __restrict__ link_state, const float* __restrict__ wx,
    const float* __restrict__ bx, float* __restrict__ LX)
{
  __shared__ float ls[4][DIM];
  int g  = threadIdx.x;           // 0..191
  int l0 = blockIdx.x*4;
  if (g < DIM){
    #pragma unroll
    for (int li=0; li<4; li++) ls[li][g] = link_state[(l0+li)*DIM+g];
  }
  __syncthreads();
  float b = bx[g];
  float a0=b, a1=b, a2=b, a3=b;
  #pragma unroll 8
  for (int k=0;k<DIM;k++){
    float w = wx[k*G3+g];
    a0 = fmaf(ls[0][k], w, a0);
    a1 = fmaf(ls[1][k], w, a1);
    a2 = fmaf(ls[2][k], w, a2);
    a3 = fmaf(ls[3][k], w, a3);
  }
  LX[(l0+0)*G3+g]=a0; LX[(l0+1)*G3+g]=a1; LX[(l0+2)*G3+g]=a2; LX[(l0+3)*G3+g]=a3;
}

// ---------------- fused 8-step GRU scan over paths. wave = 64 j-lanes x 4 paths ----------------
__global__ __launch_bounds__(256) void path_scan(
    const float* __restrict__ LX, const int* __restrict__ ltp,
    const float* __restrict__ wh, const float* __restrict__ bh,
    float* __restrict__ path_state, float* __restrict__ seq)
{
  __shared__ float  whs[DIM*G3];   // 48 KB, [k][192] original layout -> lane-consecutive reads
  __shared__ float4 hsh[4*DIM];    // [wave][k] -> 4 paths' h[k], broadcast read
  int tid = threadIdx.x;
  int j = tid & 63, w = tid >> 6;
  for (int i = tid; i < DIM*G3; i += 256) whs[i] = wh[i];
  int p0 = blockIdx.x*16 + w*4;
  float bz = bh[j], br = bh[64+j], bq = bh[128+j];
  float h0 = path_state[(p0+0)*DIM+j];
  float h1 = path_state[(p0+1)*DIM+j];
  float h2 = path_state[(p0+2)*DIM+j];
  float h3 = path_state[(p0+3)*DIM+j];
  hsh[w*DIM+j] = make_float4(h0,h1,h2,h3);
  __syncthreads();
  for (int t=0;t<LPATH;t++){
    const float* lx0 = LX + (long)ltp[(p0+0)*LPATH+t]*G3;
    const float* lx1 = LX + (long)ltp[(p0+1)*LPATH+t]*G3;
    const float* lx2 = LX + (long)ltp[(p0+2)*LPATH+t]*G3;
    const float* lx3 = LX + (long)ltp[(p0+3)*LPATH+t]*G3;
    float az0 = lx0[j]+bz,      az1 = lx1[j]+bz,      az2 = lx2[j]+bz,      az3 = lx3[j]+bz;
    float ar0 = lx0[64+j]+br,   ar1 = lx1[64+j]+br,   ar2 = lx2[64+j]+br,   ar3 = lx3[64+j]+br;
    float xq0 = lx0[128+j],     xq1 = lx1[128+j],     xq2 = lx2[128+j],     xq3 = lx3[128+j];
    float rq0 = bq, rq1 = bq, rq2 = bq, rq3 = bq;
    #pragma unroll 8
    for (int k=0;k<DIM;k++){
      float4 hv = hsh[w*DIM+k];
      float wz = whs[k*G3+j];
      float wr = whs[k*G3+64+j];
      float wq = whs[k*G3+128+j];
      az0 = fmaf(hv.x,wz,az0); az1 = fmaf(hv.y,wz,az1); az2 = fmaf(hv.z,wz,az2); az3 = fmaf(hv.w,wz,az3);
      ar0 = fmaf(hv.x,wr,ar0); ar1 = fmaf(hv.y,wr,ar1); ar2 = fmaf(hv.z,wr,ar2); ar3 = fmaf(hv.w,wr,ar3);
      rq0 = fmaf(hv.x,wq,rq0); rq1 = fmaf(hv.y,wq,rq1); rq2 = fmaf(hv.z,wq,rq2); rq3 = fmaf(hv.w,wq,rq3);
    }
    float z0=fsigmoid(az0), z1=fsigmoid(az1), z2=fsigmoid(az2), z3=fsigmoid(az3);
    float r0=fsigmoid(ar0), r1=fsigmoid(ar1), r2=fsigmoid(ar2), r3=fsigmoid(ar3);
    float q0=ftanh(fmaf(r0,rq0,xq0)), q1=ftanh(fmaf(r1,rq1,xq1));
    float q2=ftanh(fmaf(r2,rq2,xq2)), q3=ftanh(fmaf(r3,rq3,xq3));
    h0 = z0*h0 + (1.f-z0)*q0;
    h1 = z1*h1 + (1.f-z1)*q1;
    h2 = z2*h2 + (1.f-z2)*q2;
    h3 = z3*h3 + (1.f-z3)*q3;
    seq[((p0+0)*LPATH+t)*DIM+j] = h0;
    seq[((p0+1)*LPATH+t)*DIM+j] = h1;
    seq[((p0+2)*LPATH+t)*DIM+j] = h2;
    seq[((p0+3)*LPATH+t)*DIM+j] = h3;
    hsh[w*DIM+j] = make_float4(h0,h1,h2,h3);
    __syncthreads();
  }
  path_state[(p0+0)*DIM+j] = h0;
  path_state[(p0+1)*DIM+j] = h1;
  path_state[(p0+2)*DIM+j] = h2;
  path_state[(p0+3)*DIM+j] = h3;
}

// ---------------- link update: path_sum gather + link GRU. 10 links/block ----------------
#define LPB 10
__global__ __launch_bounds__(256) void link_update(
    const float* __restrict__ seq, const int* __restrict__ ptl,
    const float* __restrict__ wx, const float* __restrict__ whm,
    const float* __restrict__ bx, const float* __restrict__ bhm,
    float* __restrict__ link_state)
{
  __shared__ float psp[4][DIM];
  __shared__ float ps[DIM];
  __shared__ float ls[DIM];
  __shared__ float mx[G3], mh[G3];
  int tid = threadIdx.x;
  int c = tid >> 6, k = tid & 63;
  for (int li=0; li<LPB; li++){
    int l = blockIdx.x*LPB + li;
    float s = 0.f;
    #pragma unroll
    for (int d = c*10; d < c*10+10; d++){
      int pp = ptl[(l*DEG+d)*2+0];
      int tt = ptl[(l*DEG+d)*2+1];      // 1..8 -> seq row tt-1
      s += seq[(pp*LPATH + (tt-1))*DIM + k];
    }
    psp[c][k] = s;
    if (tid < DIM) ls[tid] = link_state[l*DIM+tid];
    __syncthreads();
    if (tid < DIM) ps[tid] = psp[0][tid]+psp[1][tid]+psp[2][tid]+psp[3][tid];
    __syncthreads();
    if (tid < G3){
      float ax = bx[tid], ah = bhm[tid];
      #pragma unroll 8
      for (int kk=0;kk<DIM;kk++){
        ax = fmaf(ps[kk], wx[kk*G3+tid], ax);
        ah = fmaf(ls[kk], whm[kk*G3+tid], ah);
      }
      mx[tid]=ax; mh[tid]=ah;
    }
    __syncthreads();
    if (tid < DIM){
      float z = fsigmoid(mx[tid]+mh[tid]);
      float r = fsigmoid(mx[64+tid]+mh[64+tid]);
      float q = ftanh(fmaf(r, mh[128+tid], mx[128+tid]));
      link_state[l*DIM+tid] = z*ls[tid] + (1.f-z)*q;
    }
    __syncthreads();
  }
}

// ---------------- readout MLP + delay reduction. thread = (path, t) ----------------
__global__ __launch_bounds__(256) void readout(
    const float* __restrict__ seq, const int* __restrict__ ltp, const float* __restrict__ cap,
    const float* __restrict__ w1, const float* __restrict__ b1,
    const float* __restrict__ w2, const float* __restrict__ b2,
    const float* __restrict__ w3, const float* __restrict__ b3,
    float* __restrict__ out)
{
  __shared__ float w1s[DIM*32];
  __shared__ float w2s[32*16];
  __shared__ float w3s[16];
  __shared__ float b1s[32], b2s[16];
  int tid = threadIdx.x;
  for (int i=tid;i<DIM*32;i+=256) w1s[i]=w1[i];
  for (int i=tid;i<32*16;i+=256) w2s[i]=w2[i];
  if (tid<16) w3s[tid]=w3[tid];
  if (tid<32) b1s[tid]=b1[tid];
  if (tid<16) b2s[tid]=b2[tid];
  __syncthreads();
  int gi = blockIdx.x*256 + tid;
  if (gi < N_PATHS*LPATH){
    int p = gi >> 3, t = gi & 7;
    float a[32];
    #pragma unroll
    for (int j=0;j<32;j++) a[j]=b1s[j];
    const float4* row = (const float4*)(seq + (size_t)(p*LPATH+t)*DIM);
    #pragma unroll
    for (int k4=0;k4<16;k4++){
      float4 rv = row[k4];
      float rr[4] = {rv.x, rv.y, rv.z, rv.w};
      #pragma unroll
      for (int kk=0;kk<4;kk++){
        #pragma unroll
        for (int j=0;j<32;j++) a[j] = fmaf(rr[kk], w1s[(k4*4+kk)*32+j], a[j]);
      }
    }
    float h2[16];
    #pragma unroll
    for (int j2=0;j2<16;j2++) h2[j2]=b2s[j2];
    #pragma unroll
    for (int j=0;j<32;j++){
      float hv = fmaxf(a[j],0.f);
      #pragma unroll
      for (int j2=0;j2<16;j2++) h2[j2] = fmaf(hv, w2s[j*16+j2], h2[j2]);
    }
    float o = b3[0];
    #pragma unroll
    for (int j2=0;j2<16;j2++) o = fmaf(fmaxf(h2[j2],0.f), w3s[j2], o);
    float sp = (o > 20.f) ? o : log1pf(__expf(o));
    float dly = sp / cap[ltp[p*LPATH + t]];
    dly += __shfl_xor(dly, 1);
    dly += __shfl_xor(dly, 2);
    dly += __shfl_xor(dly, 4);
    if (t == 0) out[p] = dly;
  }
}

extern "C" void kernel_launch(void* const* d_in, const int* in_sizes, int n_in,
                              void* d_out, int out_size, void* d_ws, size_t ws_size,
                              hipStream_t stream) {
  const float* ft    = (const float*)d_in[0];
  const float* fpk   = (const float*)d_in[1];
  const float* fps   = (const float*)d_in[2];
  const float* cap   = (const float*)d_in[3];
  const int*   ltp   = (const int*)  d_in[4];
  const int*   ptl   = (const int*)  d_in[5];
  const float* pe_w1 = (const float*)d_in[6];
  const float* pe_b1 = (const float*)d_in[7];
  const float* pe_w2 = (const float*)d_in[8];
  const float* pe_b2 = (const float*)d_in[9];
  const float* le_w1 = (const float*)d_in[10];
  const float* le_b1 = (const float*)d_in[11];
  const float* le_w2 = (const float*)d_in[12];
  const float* le_b2 = (const float*)d_in[13];
  const float* pg_wx = (const float*)d_in[14];
  const float* pg_wh = (const float*)d_in[15];
  const float* pg_bx = (const float*)d_in[16];
  const float* pg_bh = (const float*)d_in[17];
  const float* lg_wx = (const float*)d_in[18];
  const float* lg_wh = (const float*)d_in[19];
  const float* lg_bx = (const float*)d_in[20];
  const float* lg_bh = (const float*)d_in[21];
  const float* ro_w1 = (const float*)d_in[22];
  const float* ro_b1 = (const float*)d_in[23];
  const float* ro_w2 = (const float*)d_in[24];
  const float* ro_b2 = (const float*)d_in[25];
  const float* ro_w3 = (const float*)d_in[26];
  const float* ro_b3 = (const float*)d_in[27];
  float* out = (float*)d_out;

  float* path_state = (float*)d_ws;                         // 50000*64
  float* link_state = path_state + (size_t)N_PATHS*DIM;     // 10000*64
  float* LX         = link_state + (size_t)N_LINKS*DIM;     // 10000*192
  float* seq        = LX + (size_t)N_LINKS*G3;              // 50000*8*64

  path_embed<<<N_PATHS/4, 256, 0, stream>>>(ft, fpk, fps, pe_w1, pe_b1, pe_w2, pe_b2, path_state);
  link_embed<<<N_LINKS/4, 256, 0, stream>>>(ft, cap, ptl, le_w1, le_b1, le_w2, le_b2, link_state);
  compute_lx<<<N_LINKS/4, 192, 0, stream>>>(link_state, pg_wx, pg_bx, LX);
  for (int it=0; it<ITERS; ++it){
    path_scan<<<N_PATHS/16, 256, 0, stream>>>(LX, ltp, pg_wh, pg_bh, path_state, seq);
    link_update<<<N_LINKS/LPB, 256, 0, stream>>>(seq, ptl, lg_wx, lg_wh, lg_bx, lg_bh, link_state);
    if (it < ITERS-1)
      compute_lx<<<N_LINKS/4, 192, 0, stream>>>(link_state, pg_wx, pg_bx, LX);
  }
  readout<<<(N_PATHS*LPATH + 255)/256, 256, 0, stream>>>(seq, ltp, cap,
      ro_w1, ro_b1, ro_w2, ro_b2, ro_w3, ro_b3, out);
}

// Round 2
// 1245.344 us; speedup vs baseline: 1.7692x; 1.7692x over previous
//
#include <hip/hip_runtime.h>
#include <math.h>

#define N_PATHS 50000
#define N_LINKS 10000
#define LPATH   8
#define DEG     40
#define DIM     64
#define G3      192
#define ITERS   8
#define PAD     76   // floats per h-row in LDS: 304B, 16B-aligned rows, 2-way write conflicts

typedef float f32x4  __attribute__((ext_vector_type(4)));
typedef short bf16x8 __attribute__((ext_vector_type(8)));

__device__ __forceinline__ float fsigmoid(float x){ return 1.0f/(1.0f + __expf(-x)); }
__device__ __forceinline__ float ftanh(float x){ return 1.0f - 2.0f/(__expf(2.0f*x) + 1.0f); }
__device__ __forceinline__ unsigned short bf16_rne(float v){
  unsigned u = __float_as_uint(v);
  return (unsigned short)((u + 0x7FFFu + ((u>>16)&1u)) >> 16);
}

// ---------------- path embedding: thread=(path_local, j), 4 paths/block ----------------
__global__ __launch_bounds__(256) void path_embed(
    const float* __restrict__ ft, const float* __restrict__ fp, const float* __restrict__ fps,
    const float* __restrict__ w1, const float* __restrict__ b1,
    const float* __restrict__ w2, const float* __restrict__ b2,
    float* __restrict__ path_state)
{
  __shared__ float h1[4][DIM];
  int j  = threadIdx.x & 63;
  int pl = threadIdx.x >> 6;
  int p  = blockIdx.x*4 + pl;
  float x0 = ft[p]*1e-4f, x1 = fp[p]*1e-3f, x2 = fps[p]*1e-3f;
  float h = b1[j] + x0*w1[0*DIM+j] + x1*w1[1*DIM+j] + x2*w1[2*DIM+j];
  h1[pl][j] = fmaxf(h, 0.f);
  __syncthreads();
  float acc = b2[j];
  #pragma unroll 8
  for (int k=0;k<DIM;k++) acc = fmaf(h1[pl][k], w2[k*DIM+j], acc);
  path_state[p*DIM+j] = fmaxf(acc, 0.f);
}

// ---------------- link embedding (incl. load computation), wave = 1 link ----------------
__global__ __launch_bounds__(256) void link_embed(
    const float* __restrict__ ft, const float* __restrict__ cap, const int* __restrict__ ptl,
    const float* __restrict__ w1, const float* __restrict__ b1,
    const float* __restrict__ w2, const float* __restrict__ b2,
    float* __restrict__ link_state)
{
  __shared__ float h1[4][DIM];
  int j  = threadIdx.x & 63;
  int wl = threadIdx.x >> 6;
  int l  = blockIdx.x*4 + wl;
  float s = 0.f;
  if (j < DEG) s = ft[ptl[(l*DEG + j)*2 + 0]];
  #pragma unroll
  for (int off=32; off; off>>=1) s += __shfl_down(s, off);
  float load = __shfl(s, 0) / (cap[l]*1e9f);
  float x0 = cap[l]*1e-5f;
  float h = b1[j] + x0*w1[0*DIM+j] + load*w1[1*DIM+j];
  h1[wl][j] = fmaxf(h, 0.f);
  __syncthreads();
  float acc = b2[j];
  #pragma unroll 8
  for (int k=0;k<DIM;k++) acc = fmaf(h1[wl][k], w2[k*DIM+j], acc);
  link_state[l*DIM+j] = fmaxf(acc, 0.f);
}

// ---------------- pre-pack pg_wh into bf16 MFMA B-fragments ----------------
// frag f = nt*2+kc (nt 0..11, kc 0..1). elem i of lane l = wh[kc*32+(l>>4)*8+i][nt*16+(l&15)]
// stored at whf[f*512 + l*8 + i]
__global__ __launch_bounds__(256) void wh_frags(const float* __restrict__ wh,
                                                unsigned short* __restrict__ whf)
{
  int tid = blockIdx.x*256 + threadIdx.x;
  if (tid >= 24*64*8) return;
  int i = tid & 7, l = (tid>>3)&63, f = tid>>9;
  int nt = f>>1, kc = f&1;
  int k = kc*32 + (l>>4)*8 + i;
  int n = nt*16 + (l&15);
  whf[tid] = bf16_rne(wh[k*G3 + n]);
}

// ---------------- LX = link_state @ pg_wx + pg_bx (+ pg_bh folded into z,r thirds) ----------------
__global__ __launch_bounds__(192) void compute_lx(
    const float* __restrict__ link_state, const float* __restrict__ wx,
    const float* __restrict__ bx, const float* __restrict__ bh, float* __restrict__ LX)
{
  __shared__ float ls[4][DIM];
  int g  = threadIdx.x;           // 0..191
  int l0 = blockIdx.x*4;
  if (g < DIM){
    #pragma unroll
    for (int li=0; li<4; li++) ls[li][g] = link_state[(l0+li)*DIM+g];
  }
  __syncthreads();
  float b = bx[g] + (g < 128 ? bh[g] : 0.f);
  float a0=b, a1=b, a2=b, a3=b;
  #pragma unroll 8
  for (int k=0;k<DIM;k++){
    float w = wx[k*G3+g];
    a0 = fmaf(ls[0][k], w, a0);
    a1 = fmaf(ls[1][k], w, a1);
    a2 = fmaf(ls[2][k], w, a2);
    a3 = fmaf(ls[3][k], w, a3);
  }
  LX[(l0+0)*G3+g]=a0; LX[(l0+1)*G3+g]=a1; LX[(l0+2)*G3+g]=a2; LX[(l0+3)*G3+g]=a3;
}

// ---------------- MFMA 8-step GRU scan. wave = 16 paths, block = 4 waves, no barriers ----------------
__global__ __launch_bounds__(256) void path_scan_mfma(
    const float* __restrict__ LX, const int* __restrict__ ltp,
    const unsigned short* __restrict__ whf, const float* __restrict__ bh,
    float* __restrict__ path_state, float* __restrict__ seq)
{
  __shared__ float htile[4][16*PAD];   // per-wave h [16 paths][64 dims], padded
  __shared__ int   ltps[4][128];       // per-wave 16 paths x 8 link ids
  int tid = threadIdx.x, l = tid & 63, w = tid >> 6;
  int lg = l >> 4, lr = l & 15;
  int p0 = blockIdx.x*64 + w*16;
  if (p0 >= N_PATHS) return;           // wave-uniform exit (no block barriers anywhere)

  // weight fragments -> 96 VGPRs (L2-broadcast across all blocks)
  bf16x8 bf[12][2];
  #pragma unroll
  for (int nt=0; nt<12; nt++){
    #pragma unroll
    for (int kc=0; kc<2; kc++)
      bf[nt][kc] = *(const bf16x8*)(whf + (nt*2+kc)*512 + l*8);
  }
  float bhq[4];
  #pragma unroll
  for (int q=0;q<4;q++) bhq[q] = bh[128 + q*16 + lr];

  // stage link ids for this wave's 16 paths
  *(int2*)&ltps[w][l*2] = *(const int2*)(ltp + (size_t)p0*LPATH + l*2);

  // stage initial h into LDS (coalesced float4 reads, scalar LDS writes)
  #pragma unroll
  for (int rep=0; rep<4; rep++){
    int idx = rep*64 + l;
    int pi = idx >> 4, dc = idx & 15;
    float4 v = *(const float4*)(path_state + (size_t)(p0+pi)*DIM + dc*4);
    float* dst = &htile[w][pi*PAD + dc*4];
    dst[0]=v.x; dst[1]=v.y; dst[2]=v.z; dst[3]=v.w;
  }
  // h_old in registers, D-fragment layout: hold[nt][r] = h[path 4*lg+r][nt*16+lr]
  f32x4 hold[4];
  #pragma unroll
  for (int nt=0;nt<4;nt++){
    #pragma unroll
    for (int r=0;r<4;r++)
      hold[nt][r] = htile[w][(lg*4+r)*PAD + nt*16 + lr];
  }

  for (int t=0; t<LPATH; t++){
    f32x4 acc[12]; f32x4 xq[4];
    // gather LX rows straight into accumulators (bh_z/bh_r already folded into LX)
    #pragma unroll
    for (int r=0;r<4;r++){
      int lk = ltps[w][(lg*4+r)*LPATH + t];
      const float* lxr = LX + (size_t)lk*G3;
      #pragma unroll
      for (int nt=0;nt<8;nt++) acc[nt][r] = lxr[nt*16+lr];
      #pragma unroll
      for (int q=0;q<4;q++){ xq[q][r] = lxr[128+q*16+lr]; acc[8+q][r] = bhq[q]; }
    }
    // A-fragments from LDS (exact hi+lo bf16 split), 24 MFMAs per split-term
    #pragma unroll
    for (int kc=0;kc<2;kc++){
      const float* hrow = &htile[w][lr*PAD + kc*32 + lg*8];
      f32x4 h0 = *(const f32x4*)(hrow);
      f32x4 h1 = *(const f32x4*)(hrow+4);
      bf16x8 ahi, alo;
      #pragma unroll
      for (int e=0;e<4;e++){
        unsigned short hb = bf16_rne(h0[e]);
        float lof = h0[e] - __uint_as_float((unsigned)hb<<16);
        ahi[e] = (short)hb; alo[e] = (short)bf16_rne(lof);
      }
      #pragma unroll
      for (int e=0;e<4;e++){
        unsigned short hb = bf16_rne(h1[e]);
        float lof = h1[e] - __uint_as_float((unsigned)hb<<16);
        ahi[4+e] = (short)hb; alo[4+e] = (short)bf16_rne(lof);
      }
      #pragma unroll
      for (int nt=0;nt<12;nt++){
        acc[nt] = __builtin_amdgcn_mfma_f32_16x16x32_bf16(ahi, bf[nt][kc], acc[nt], 0,0,0);
        acc[nt] = __builtin_amdgcn_mfma_f32_16x16x32_bf16(alo, bf[nt][kc], acc[nt], 0,0,0);
      }
    }
    // gates + blend (all lane-local), write back h to LDS + seq
    #pragma unroll
    for (int nt=0;nt<4;nt++){
      #pragma unroll
      for (int r=0;r<4;r++){
        float z  = fsigmoid(acc[nt][r]);
        float rr = fsigmoid(acc[4+nt][r]);
        float hh = ftanh(xq[nt][r] + rr*acc[8+nt][r]);
        float hn = z*hold[nt][r] + (1.f-z)*hh;
        hold[nt][r] = hn;
        htile[w][(lg*4+r)*PAD + nt*16 + lr] = hn;
        seq[((size_t)(p0+lg*4+r)*LPATH + t)*DIM + nt*16 + lr] = hn;
      }
    }
  }
  #pragma unroll
  for (int nt=0;nt<4;nt++){
    #pragma unroll
    for (int r=0;r<4;r++)
      path_state[(size_t)(p0+lg*4+r)*DIM + nt*16 + lr] = hold[nt][r];
  }
}

// ---------------- link update: one link per block ----------------
__global__ __launch_bounds__(256) void link_update(
    const float* __restrict__ seq, const int* __restrict__ ptl,
    const float* __restrict__ wx, const float* __restrict__ whm,
    const float* __restrict__ bx, const float* __restrict__ bhm,
    float* __restrict__ link_state)
{
  __shared__ float psp[4][DIM];
  __shared__ float ps[DIM];
  __shared__ float ls[DIM];
  __shared__ float mx[G3], mh[G3];
  int tid = threadIdx.x;
  int c = tid >> 6, k = tid & 63;
  int lnk = blockIdx.x;
  float s = 0.f;
  #pragma unroll
  for (int d = c*10; d < c*10+10; d++){
    int pp = ptl[(lnk*DEG+d)*2+0];
    int tt = ptl[(lnk*DEG+d)*2+1];      // 1..8 -> seq row tt-1
    s += seq[((size_t)pp*LPATH + (tt-1))*DIM + k];
  }
  psp[c][k] = s;
  if (tid < DIM) ls[tid] = link_state[lnk*DIM+tid];
  __syncthreads();
  if (tid < DIM) ps[tid] = psp[0][tid]+psp[1][tid]+psp[2][tid]+psp[3][tid];
  __syncthreads();
  if (tid < G3){
    float ax = bx[tid], ah = bhm[tid];
    #pragma unroll 8
    for (int kk=0;kk<DIM;kk++){
      ax = fmaf(ps[kk], wx[kk*G3+tid], ax);
      ah = fmaf(ls[kk], whm[kk*G3+tid], ah);
    }
    mx[tid]=ax; mh[tid]=ah;
  }
  __syncthreads();
  if (tid < DIM){
    float z = fsigmoid(mx[tid]+mh[tid]);
    float r = fsigmoid(mx[64+tid]+mh[64+tid]);
    float q = ftanh(fmaf(r, mh[128+tid], mx[128+tid]));
    link_state[lnk*DIM+tid] = z*ls[tid] + (1.f-z)*q;
  }
}

// ---------------- readout MLP + delay reduction. thread = (path, t) ----------------
__global__ __launch_bounds__(256) void readout(
    const float* __restrict__ seq, const int* __restrict__ ltp, const float* __restrict__ cap,
    const float* __restrict__ w1, const float* __restrict__ b1,
    const float* __restrict__ w2, const float* __restrict__ b2,
    const float* __restrict__ w3, const float* __restrict__ b3,
    float* __restrict__ out)
{
  __shared__ float w1s[DIM*32];
  __shared__ float w2s[32*16];
  __shared__ float w3s[16];
  __shared__ float b1s[32], b2s[16];
  int tid = threadIdx.x;
  for (int i=tid;i<DIM*32;i+=256) w1s[i]=w1[i];
  for (int i=tid;i<32*16;i+=256) w2s[i]=w2[i];
  if (tid<16) w3s[tid]=w3[tid];
  if (tid<32) b1s[tid]=b1[tid];
  if (tid<16) b2s[tid]=b2[tid];
  __syncthreads();
  int gi = blockIdx.x*256 + tid;
  if (gi < N_PATHS*LPATH){
    int p = gi >> 3, t = gi & 7;
    float a[32];
    #pragma unroll
    for (int j=0;j<32;j++) a[j]=b1s[j];
    const float4* row = (const float4*)(seq + (size_t)(p*LPATH+t)*DIM);
    #pragma unroll
    for (int k4=0;k4<16;k4++){
      float4 rv = row[k4];
      float rr[4] = {rv.x, rv.y, rv.z, rv.w};
      #pragma unroll
      for (int kk=0;kk<4;kk++){
        #pragma unroll
        for (int j=0;j<32;j++) a[j] = fmaf(rr[kk], w1s[(k4*4+kk)*32+j], a[j]);
      }
    }
    float h2[16];
    #pragma unroll
    for (int j2=0;j2<16;j2++) h2[j2]=b2s[j2];
    #pragma unroll
    for (int j=0;j<32;j++){
      float hv = fmaxf(a[j],0.f);
      #pragma unroll
      for (int j2=0;j2<16;j2++) h2[j2] = fmaf(hv, w2s[j*16+j2], h2[j2]);
    }
    float o = b3[0];
    #pragma unroll
    for (int j2=0;j2<16;j2++) o = fmaf(fmaxf(h2[j2],0.f), w3s[j2], o);
    float sp = (o > 20.f) ? o : log1pf(__expf(o));
    float dly = sp / cap[ltp[p*LPATH + t]];
    dly += __shfl_xor(dly, 1);
    dly += __shfl_xor(dly, 2);
    dly += __shfl_xor(dly, 4);
    if (t == 0) out[p] = dly;
  }
}

extern "C" void kernel_launch(void* const* d_in, const int* in_sizes, int n_in,
                              void* d_out, int out_size, void* d_ws, size_t ws_size,
                              hipStream_t stream) {
  const float* ft    = (const float*)d_in[0];
  const float* fpk   = (const float*)d_in[1];
  const float* fps   = (const float*)d_in[2];
  const float* cap   = (const float*)d_in[3];
  const int*   ltp   = (const int*)  d_in[4];
  const int*   ptl   = (const int*)  d_in[5];
  const float* pe_w1 = (const float*)d_in[6];
  const float* pe_b1 = (const float*)d_in[7];
  const float* pe_w2 = (const float*)d_in[8];
  const float* pe_b2 = (const float*)d_in[9];
  const float* le_w1 = (const float*)d_in[10];
  const float* le_b1 = (const float*)d_in[11];
  const float* le_w2 = (const float*)d_in[12];
  const float* le_b2 = (const float*)d_in[13];
  const float* pg_wx = (const float*)d_in[14];
  const float* pg_wh = (const float*)d_in[15];
  const float* pg_bx = (const float*)d_in[16];
  const float* pg_bh = (const float*)d_in[17];
  const float* lg_wx = (const float*)d_in[18];
  const float* lg_wh = (const float*)d_in[19];
  const float* lg_bx = (const float*)d_in[20];
  const float* lg_bh = (const float*)d_in[21];
  const float* ro_w1 = (const float*)d_in[22];
  const float* ro_b1 = (const float*)d_in[23];
  const float* ro_w2 = (const float*)d_in[24];
  const float* ro_b2 = (const float*)d_in[25];
  const float* ro_w3 = (const float*)d_in[26];
  const float* ro_b3 = (const float*)d_in[27];
  float* out = (float*)d_out;

  float* path_state = (float*)d_ws;                          // 50000*64
  float* link_state = path_state + (size_t)N_PATHS*DIM;      // 10000*64
  float* LX         = link_state + (size_t)N_LINKS*DIM;      // 10000*192
  float* seq        = LX + (size_t)N_LINKS*G3;               // 50000*8*64
  unsigned short* whf = (unsigned short*)(seq + (size_t)N_PATHS*LPATH*DIM); // 24*512 bf16

  path_embed<<<N_PATHS/4, 256, 0, stream>>>(ft, fpk, fps, pe_w1, pe_b1, pe_w2, pe_b2, path_state);
  link_embed<<<N_LINKS/4, 256, 0, stream>>>(ft, cap, ptl, le_w1, le_b1, le_w2, le_b2, link_state);
  wh_frags<<<48, 256, 0, stream>>>(pg_wh, whf);
  compute_lx<<<N_LINKS/4, 192, 0, stream>>>(link_state, pg_wx, pg_bx, pg_bh, LX);
  for (int it=0; it<ITERS; ++it){
    path_scan_mfma<<<(N_PATHS+63)/64, 256, 0, stream>>>(LX, ltp, whf, pg_bh, path_state, seq);
    link_update<<<N_LINKS, 256, 0, stream>>>(seq, ptl, lg_wx, lg_wh, lg_bx, lg_bh, link_state);
    if (it < ITERS-1)
      compute_lx<<<N_LINKS/4, 192, 0, stream>>>(link_state, pg_wx, pg_bx, pg_bh, LX);
  }
  readout<<<(N_PATHS*LPATH + 255)/256, 256, 0, stream>>>(seq, ltp, cap,
      ro_w1, ro_b1, ro_w2, ro_b2, ro_w3, ro_b3, out);
}

// Round 3
// 895.024 us; speedup vs baseline: 2.4616x; 1.3914x over previous
//
#include <hip/hip_runtime.h>
#include <math.h>

#define N_PATHS 50000
#define N_LINKS 10000
#define LPATH   8
#define DEG     40
#define DIM     64
#define G3      192
#define ITERS   8
#define PAD     76   // floats per h-row in path_scan LDS tile

typedef float f32x4  __attribute__((ext_vector_type(4)));
typedef short bf16x8 __attribute__((ext_vector_type(8)));

__device__ __forceinline__ float fsigmoid(float x){ return 1.0f/(1.0f + __expf(-x)); }
__device__ __forceinline__ float ftanh(float x){ return 1.0f - 2.0f/(__expf(2.0f*x) + 1.0f); }
__device__ __forceinline__ unsigned short bf16_rne(float v){
  unsigned u = __float_as_uint(v);
  return (unsigned short)((u + 0x7FFFu + ((u>>16)&1u)) >> 16);
}
__device__ __forceinline__ float bf2f(unsigned short s){
  return __uint_as_float(((unsigned)s)<<16);
}
// split 8 fp32 into bf16 hi + bf16 residual fragments (near-exact A operand)
__device__ __forceinline__ void split8(const float* s, bf16x8& hi, bf16x8& lo){
  #pragma unroll
  for (int e=0;e<8;e++){
    unsigned short hb = bf16_rne(s[e]);
    float lof = s[e] - __uint_as_float(((unsigned)hb)<<16);
    hi[e] = (short)hb; lo[e] = (short)bf16_rne(lof);
  }
}
__device__ __forceinline__ void accum8(float* a, uint4 v){
  unsigned x[4] = {v.x, v.y, v.z, v.w};
  #pragma unroll
  for (int q=0;q<4;q++){
    a[2*q]   += __uint_as_float((x[q]&0xFFFFu)<<16);
    a[2*q+1] += __uint_as_float(x[q]&0xFFFF0000u);
  }
}

// ---------------- path embedding ----------------
__global__ __launch_bounds__(256) void path_embed(
    const float* __restrict__ ft, const float* __restrict__ fp, const float* __restrict__ fps,
    const float* __restrict__ w1, const float* __restrict__ b1,
    const float* __restrict__ w2, const float* __restrict__ b2,
    float* __restrict__ path_state)
{
  __shared__ float h1[4][DIM];
  int j  = threadIdx.x & 63;
  int pl = threadIdx.x >> 6;
  int p  = blockIdx.x*4 + pl;
  float x0 = ft[p]*1e-4f, x1 = fp[p]*1e-3f, x2 = fps[p]*1e-3f;
  float h = b1[j] + x0*w1[0*DIM+j] + x1*w1[1*DIM+j] + x2*w1[2*DIM+j];
  h1[pl][j] = fmaxf(h, 0.f);
  __syncthreads();
  float acc = b2[j];
  #pragma unroll 8
  for (int k=0;k<DIM;k++) acc = fmaf(h1[pl][k], w2[k*DIM+j], acc);
  path_state[p*DIM+j] = fmaxf(acc, 0.f);
}

// ---------------- link embedding ----------------
__global__ __launch_bounds__(256) void link_embed(
    const float* __restrict__ ft, const float* __restrict__ cap, const int* __restrict__ ptl,
    const float* __restrict__ w1, const float* __restrict__ b1,
    const float* __restrict__ w2, const float* __restrict__ b2,
    float* __restrict__ link_state)
{
  __shared__ float h1[4][DIM];
  int j  = threadIdx.x & 63;
  int wl = threadIdx.x >> 6;
  int l  = blockIdx.x*4 + wl;
  float s = 0.f;
  if (j < DEG) s = ft[ptl[(l*DEG + j)*2 + 0]];
  #pragma unroll
  for (int off=32; off; off>>=1) s += __shfl_down(s, off);
  float load = __shfl(s, 0) / (cap[l]*1e9f);
  float x0 = cap[l]*1e-5f;
  float h = b1[j] + x0*w1[0*DIM+j] + load*w1[1*DIM+j];
  h1[wl][j] = fmaxf(h, 0.f);
  __syncthreads();
  float acc = b2[j];
  #pragma unroll 8
  for (int k=0;k<DIM;k++) acc = fmaf(h1[wl][k], w2[k*DIM+j], acc);
  link_state[l*DIM+j] = fmaxf(acc, 0.f);
}

// ---------------- pack 4 weight mats into bf16 MFMA B-fragments ----------------
// m: 0=pg_wh, 1=pg_wx, 2=lg_wx, 3=lg_wh. frag f=nt*2+kc.
// elem i of lane l = w[kc*32+(l>>4)*8+i][nt*16+(l&15)], at whf[((m*24+f)*512) + l*8 + i]
__global__ __launch_bounds__(256) void pack_frags(
    const float* __restrict__ pg_wh, const float* __restrict__ pg_wx,
    const float* __restrict__ lg_wx, const float* __restrict__ lg_wh,
    unsigned short* __restrict__ whf)
{
  int tid = blockIdx.x*256 + threadIdx.x;
  if (tid >= 4*24*512) return;
  int i = tid & 7, l = (tid>>3)&63, f = (tid>>9)%24, m = tid/(24*512);
  int nt = f>>1, kc = f&1;
  int k = kc*32 + (l>>4)*8 + i;
  int n = nt*16 + (l&15);
  const float* src = (m==0)?pg_wh : (m==1)?pg_wx : (m==2)?lg_wx : lg_wh;
  whf[tid] = bf16_rne(src[k*G3 + n]);
}

// ---------------- initial LX = link_state @ pg_wx + pg_bx (+pg_bh z,r fold) ----------------
__global__ __launch_bounds__(192) void compute_lx(
    const float* __restrict__ link_state, const float* __restrict__ wx,
    const float* __restrict__ bx, const float* __restrict__ bh, float* __restrict__ LX)
{
  __shared__ float ls[4][DIM];
  int g  = threadIdx.x;
  int l0 = blockIdx.x*4;
  if (g < DIM){
    #pragma unroll
    for (int li=0; li<4; li++) ls[li][g] = link_state[(l0+li)*DIM+g];
  }
  __syncthreads();
  float b = bx[g] + (g < 128 ? bh[g] : 0.f);
  float a0=b, a1=b, a2=b, a3=b;
  #pragma unroll 8
  for (int k=0;k<DIM;k++){
    float w = wx[k*G3+g];
    a0 = fmaf(ls[0][k], w, a0);
    a1 = fmaf(ls[1][k], w, a1);
    a2 = fmaf(ls[2][k], w, a2);
    a3 = fmaf(ls[3][k], w, a3);
  }
  LX[(l0+0)*G3+g]=a0; LX[(l0+1)*G3+g]=a1; LX[(l0+2)*G3+g]=a2; LX[(l0+3)*G3+g]=a3;
}

// ---------------- MFMA 8-step GRU scan. wave = 16 paths, no barriers ----------------
__global__ __launch_bounds__(256) void path_scan_mfma(
    const float* __restrict__ LX, const int* __restrict__ ltp,
    const unsigned short* __restrict__ whf, const float* __restrict__ bh,
    float* __restrict__ path_state, unsigned short* __restrict__ seq16)
{
  __shared__ float htile[4][16*PAD];
  __shared__ int   ltps[4][128];
  int tid = threadIdx.x, l = tid & 63, w = tid >> 6;
  int lg = l >> 4, lr = l & 15;
  int p0 = blockIdx.x*64 + w*16;
  if (p0 >= N_PATHS) return;           // wave-uniform exit; LDS is wave-private

  bf16x8 bf[12][2];
  #pragma unroll
  for (int nt=0; nt<12; nt++){
    #pragma unroll
    for (int kc=0; kc<2; kc++)
      bf[nt][kc] = *(const bf16x8*)(whf + (nt*2+kc)*512 + l*8);
  }
  float bhq[4];
  #pragma unroll
  for (int q=0;q<4;q++) bhq[q] = bh[128 + q*16 + lr];

  *(int2*)&ltps[w][l*2] = *(const int2*)(ltp + (size_t)p0*LPATH + l*2);

  #pragma unroll
  for (int rep=0; rep<4; rep++){
    int idx = rep*64 + l;
    int pi = idx >> 4, dc = idx & 15;
    float4 v = *(const float4*)(path_state + (size_t)(p0+pi)*DIM + dc*4);
    float* dst = &htile[w][pi*PAD + dc*4];
    dst[0]=v.x; dst[1]=v.y; dst[2]=v.z; dst[3]=v.w;
  }
  f32x4 hold[4];
  #pragma unroll
  for (int nt=0;nt<4;nt++){
    #pragma unroll
    for (int r=0;r<4;r++)
      hold[nt][r] = htile[w][(lg*4+r)*PAD + nt*16 + lr];
  }

  for (int t=0; t<LPATH; t++){
    f32x4 acc[12]; f32x4 xq[4];
    #pragma unroll
    for (int r=0;r<4;r++){
      int lk = ltps[w][(lg*4+r)*LPATH + t];
      const float* lxr = LX + (size_t)lk*G3;
      #pragma unroll
      for (int nt=0;nt<8;nt++) acc[nt][r] = lxr[nt*16+lr];
      #pragma unroll
      for (int q=0;q<4;q++){ xq[q][r] = lxr[128+q*16+lr]; acc[8+q][r] = bhq[q]; }
    }
    #pragma unroll
    for (int kc=0;kc<2;kc++){
      const float* hrow = &htile[w][lr*PAD + kc*32 + lg*8];
      float hs[8];
      *(f32x4*)hs = *(const f32x4*)hrow;
      *(f32x4*)(hs+4) = *(const f32x4*)(hrow+4);
      bf16x8 ahi, alo;
      split8(hs, ahi, alo);
      #pragma unroll
      for (int nt=0;nt<12;nt++){
        acc[nt] = __builtin_amdgcn_mfma_f32_16x16x32_bf16(ahi, bf[nt][kc], acc[nt], 0,0,0);
        acc[nt] = __builtin_amdgcn_mfma_f32_16x16x32_bf16(alo, bf[nt][kc], acc[nt], 0,0,0);
      }
    }
    #pragma unroll
    for (int nt=0;nt<4;nt++){
      #pragma unroll
      for (int r=0;r<4;r++){
        float z  = fsigmoid(acc[nt][r]);
        float rr = fsigmoid(acc[4+nt][r]);
        float hh = ftanh(xq[nt][r] + rr*acc[8+nt][r]);
        float hn = z*hold[nt][r] + (1.f-z)*hh;
        hold[nt][r] = hn;
        htile[w][(lg*4+r)*PAD + nt*16 + lr] = hn;
        seq16[((size_t)(p0+lg*4+r)*LPATH + t)*DIM + nt*16 + lr] = bf16_rne(hn);
      }
    }
  }
  #pragma unroll
  for (int nt=0;nt<4;nt++){
    #pragma unroll
    for (int r=0;r<4;r++)
      path_state[(size_t)(p0+lg*4+r)*DIM + nt*16 + lr] = hold[nt][r];
  }
}

// ---------------- fused link update: gather psum -> link GRU (MFMA) -> next LX ----------------
// 1 wave per block, 16 links per wave, 625 blocks
__global__ __launch_bounds__(64) void link_fused(
    const unsigned short* __restrict__ seq16, const int* __restrict__ ptl,
    const unsigned short* __restrict__ whf,
    const float* __restrict__ lbx, const float* __restrict__ lbh,
    const float* __restrict__ pbx, const float* __restrict__ pbh,
    float* __restrict__ link_state, float* __restrict__ LX)
{
  __shared__ float tile[16*68];
  int l = threadIdx.x, lr = l & 15, lg = l >> 4;
  int l0 = blockIdx.x*16;

  // gather path_sum directly in A-fragment layout: lane holds link=l0+lr, dims kc*32+lg*8..+8
  float ps[16];
  #pragma unroll
  for (int i=0;i<16;i++) ps[i]=0.f;
  {
    const int* pe = ptl + (size_t)(l0+lr)*DEG*2;
    for (int d=0; d<DEG; d++){
      int pp = pe[2*d], tt = pe[2*d+1];
      const unsigned short* rowp = seq16 + ((size_t)pp*LPATH + (tt-1))*DIM;
      uint4 v0 = *(const uint4*)(rowp + lg*8);
      uint4 v1 = *(const uint4*)(rowp + 32 + lg*8);
      accum8(ps, v0);
      accum8(ps+8, v1);
    }
  }

  // mx = psum @ lg_wx + lbx ; mh = ls @ lg_wh + lbh
  f32x4 mxa[12], mha[12];
  #pragma unroll
  for (int nt=0;nt<12;nt++){
    float bxv = lbx[nt*16+lr], bhv = lbh[nt*16+lr];
    mxa[nt] = (f32x4){bxv,bxv,bxv,bxv};
    mha[nt] = (f32x4){bhv,bhv,bhv,bhv};
  }
  #pragma unroll
  for (int kc=0;kc<2;kc++){
    bf16x8 phi, plo; split8(ps + kc*8, phi, plo);
    float hs[8];
    const float* lsr = link_state + (size_t)(l0+lr)*DIM + kc*32 + lg*8;
    *(f32x4*)hs = *(const f32x4*)lsr;
    *(f32x4*)(hs+4) = *(const f32x4*)(lsr+4);
    bf16x8 lhi, llo; split8(hs, lhi, llo);
    #pragma unroll
    for (int nt=0;nt<12;nt++){
      bf16x8 bwx = *(const bf16x8*)(whf + (size_t)((2*24 + nt*2+kc)*512) + l*8);
      mxa[nt] = __builtin_amdgcn_mfma_f32_16x16x32_bf16(phi, bwx, mxa[nt], 0,0,0);
      mxa[nt] = __builtin_amdgcn_mfma_f32_16x16x32_bf16(plo, bwx, mxa[nt], 0,0,0);
      bf16x8 bwh = *(const bf16x8*)(whf + (size_t)((3*24 + nt*2+kc)*512) + l*8);
      mha[nt] = __builtin_amdgcn_mfma_f32_16x16x32_bf16(lhi, bwh, mha[nt], 0,0,0);
      mha[nt] = __builtin_amdgcn_mfma_f32_16x16x32_bf16(llo, bwh, mha[nt], 0,0,0);
    }
  }

  // gates in D-layout: lane holds links l0+lg*4+r, dim nt*16+lr
  #pragma unroll
  for (int nt=0;nt<4;nt++){
    #pragma unroll
    for (int r=0;r<4;r++){
      size_t lk = (size_t)(l0 + lg*4 + r)*DIM + nt*16 + lr;
      float lsv = link_state[lk];
      float z  = fsigmoid(mxa[nt][r] + mha[nt][r]);
      float rr = fsigmoid(mxa[4+nt][r] + mha[4+nt][r]);
      float hh = ftanh(mxa[8+nt][r] + rr*mha[8+nt][r]);
      float hn = z*lsv + (1.f-z)*hh;
      link_state[lk] = hn;
      tile[(lg*4+r)*68 + nt*16 + lr] = hn;
    }
  }

  // next-iteration LX = h' @ pg_wx + pg_bx (+pg_bh fold for z,r)
  f32x4 lxa[12];
  #pragma unroll
  for (int nt=0;nt<12;nt++){
    int g = nt*16 + lr;
    float b = pbx[g] + (g < 128 ? pbh[g] : 0.f);
    lxa[nt] = (f32x4){b,b,b,b};
  }
  #pragma unroll
  for (int kc=0;kc<2;kc++){
    float hs[8];
    #pragma unroll
    for (int i=0;i<8;i++) hs[i] = tile[lr*68 + kc*32 + lg*8 + i];
    bf16x8 hhi, hlo; split8(hs, hhi, hlo);
    #pragma unroll
    for (int nt=0;nt<12;nt++){
      bf16x8 bw = *(const bf16x8*)(whf + (size_t)((1*24 + nt*2+kc)*512) + l*8);
      lxa[nt] = __builtin_amdgcn_mfma_f32_16x16x32_bf16(hhi, bw, lxa[nt], 0,0,0);
      lxa[nt] = __builtin_amdgcn_mfma_f32_16x16x32_bf16(hlo, bw, lxa[nt], 0,0,0);
    }
  }
  #pragma unroll
  for (int nt=0;nt<12;nt++){
    #pragma unroll
    for (int r=0;r<4;r++)
      LX[(size_t)(l0 + lg*4 + r)*G3 + nt*16 + lr] = lxa[nt][r];
  }
}

// ---------------- readout: LDS-staged coalesced reads + MLP + delay reduce ----------------
__global__ __launch_bounds__(256) void readout(
    const unsigned short* __restrict__ seq16, const int* __restrict__ ltp,
    const float* __restrict__ cap,
    const float* __restrict__ w1, const float* __restrict__ b1,
    const float* __restrict__ w2, const float* __restrict__ b2,
    const float* __restrict__ w3, const float* __restrict__ b3,
    float* __restrict__ out)
{
  __shared__ unsigned short rows_sh[4][64*72];  // 64 rows x (64+8 pad) bf16 per wave
  __shared__ float w1s[DIM*32];
  __shared__ float w2s[32*16];
  __shared__ float w3s[16];
  __shared__ float b1s[32], b2s[16];
  int tid = threadIdx.x;
  for (int i=tid;i<DIM*32;i+=256) w1s[i]=w1[i];
  for (int i=tid;i<32*16;i+=256) w2s[i]=w2[i];
  if (tid<16) w3s[tid]=w3[tid];
  if (tid<32) b1s[tid]=b1[tid];
  if (tid<16) b2s[tid]=b2[tid];
  __syncthreads();

  int l = tid & 63, w = tid >> 6;
  size_t wave_r = (size_t)blockIdx.x*256 + (size_t)w*64;
  if (wave_r >= (size_t)N_PATHS*LPATH) return;   // whole wave empty (400000 % 64 == 0)

  // stage 64 rows: fully coalesced 8B/lane loads -> padded LDS (wave-private, no barrier)
  const unsigned short* src = seq16 + wave_r*DIM;
  #pragma unroll
  for (int i=0;i<16;i++){
    int e  = i*64 + l;          // ushort4 index
    int ri = e >> 4;
    int c4 = e & 15;
    *(uint2*)&rows_sh[w][ri*72 + c4*4] = *(const uint2*)(src + (size_t)e*4);
  }

  // consume own row from LDS
  size_t row = wave_r + l;
  const unsigned short* myrow = &rows_sh[w][l*72];
  float a[32];
  #pragma unroll
  for (int j=0;j<32;j++) a[j]=b1s[j];
  #pragma unroll
  for (int c=0;c<16;c++){
    uint2 v = *(const uint2*)(myrow + c*4);
    float f0 = __uint_as_float((v.x & 0xFFFFu) << 16);
    float f1 = __uint_as_float(v.x & 0xFFFF0000u);
    float f2 = __uint_as_float((v.y & 0xFFFFu) << 16);
    float f3 = __uint_as_float(v.y & 0xFFFF0000u);
    #pragma unroll
    for (int j=0;j<32;j++) a[j] = fmaf(f0, w1s[(c*4+0)*32+j], a[j]);
    #pragma unroll
    for (int j=0;j<32;j++) a[j] = fmaf(f1, w1s[(c*4+1)*32+j], a[j]);
    #pragma unroll
    for (int j=0;j<32;j++) a[j] = fmaf(f2, w1s[(c*4+2)*32+j], a[j]);
    #pragma unroll
    for (int j=0;j<32;j++) a[j] = fmaf(f3, w1s[(c*4+3)*32+j], a[j]);
  }
  float h2[16];
  #pragma unroll
  for (int j2=0;j2<16;j2++) h2[j2]=b2s[j2];
  #pragma unroll
  for (int j=0;j<32;j++){
    float hv = fmaxf(a[j],0.f);
    #pragma unroll
    for (int j2=0;j2<16;j2++) h2[j2] = fmaf(hv, w2s[j*16+j2], h2[j2]);
  }
  float o = b3[0];
  #pragma unroll
  for (int j2=0;j2<16;j2++) o = fmaf(fmaxf(h2[j2],0.f), w3s[j2], o);
  float sp = (o > 20.f) ? o : log1pf(__expf(o));
  float dly = sp / cap[ltp[row]];
  dly += __shfl_xor(dly, 1);
  dly += __shfl_xor(dly, 2);
  dly += __shfl_xor(dly, 4);
  if ((l & 7) == 0) out[row >> 3] = dly;
}

extern "C" void kernel_launch(void* const* d_in, const int* in_sizes, int n_in,
                              void* d_out, int out_size, void* d_ws, size_t ws_size,
                              hipStream_t stream) {
  const float* ft    = (const float*)d_in[0];
  const float* fpk   = (const float*)d_in[1];
  const float* fps   = (const float*)d_in[2];
  const float* cap   = (const float*)d_in[3];
  const int*   ltp   = (const int*)  d_in[4];
  const int*   ptl   = (const int*)  d_in[5];
  const float* pe_w1 = (const float*)d_in[6];
  const float* pe_b1 = (const float*)d_in[7];
  const float* pe_w2 = (const float*)d_in[8];
  const float* pe_b2 = (const float*)d_in[9];
  const float* le_w1 = (const float*)d_in[10];
  const float* le_b1 = (const float*)d_in[11];
  const float* le_w2 = (const float*)d_in[12];
  const float* le_b2 = (const float*)d_in[13];
  const float* pg_wx = (const float*)d_in[14];
  const float* pg_wh = (const float*)d_in[15];
  const float* pg_bx = (const float*)d_in[16];
  const float* pg_bh = (const float*)d_in[17];
  const float* lg_wx = (const float*)d_in[18];
  const float* lg_wh = (const float*)d_in[19];
  const float* lg_bx = (const float*)d_in[20];
  const float* lg_bh = (const float*)d_in[21];
  const float* ro_w1 = (const float*)d_in[22];
  const float* ro_b1 = (const float*)d_in[23];
  const float* ro_w2 = (const float*)d_in[24];
  const float* ro_b2 = (const float*)d_in[25];
  const float* ro_w3 = (const float*)d_in[26];
  const float* ro_b3 = (const float*)d_in[27];
  float* out = (float*)d_out;

  float* path_state = (float*)d_ws;                               // 3.2e6 f32
  float* link_state = path_state + (size_t)N_PATHS*DIM;           // 6.4e5 f32
  float* LXf        = link_state + (size_t)N_LINKS*DIM;           // 1.92e6 f32
  unsigned short* seq16 = (unsigned short*)(LXf + (size_t)N_LINKS*G3);  // 25.6e6 bf16
  unsigned short* whf   = seq16 + (size_t)N_PATHS*LPATH*DIM;      // 49152 bf16

  path_embed<<<N_PATHS/4, 256, 0, stream>>>(ft, fpk, fps, pe_w1, pe_b1, pe_w2, pe_b2, path_state);
  link_embed<<<N_LINKS/4, 256, 0, stream>>>(ft, cap, ptl, le_w1, le_b1, le_w2, le_b2, link_state);
  pack_frags<<<192, 256, 0, stream>>>(pg_wh, pg_wx, lg_wx, lg_wh, whf);
  compute_lx<<<N_LINKS/4, 192, 0, stream>>>(link_state, pg_wx, pg_bx, pg_bh, LXf);
  for (int it=0; it<ITERS; ++it){
    path_scan_mfma<<<(N_PATHS+63)/64, 256, 0, stream>>>(LXf, ltp, whf, pg_bh, path_state, seq16);
    if (it < ITERS-1)
      link_fused<<<N_LINKS/16, 64, 0, stream>>>(seq16, ptl, whf,
          lg_bx, lg_bh, pg_bx, pg_bh, link_state, LXf);
  }
  readout<<<(N_PATHS*LPATH + 255)/256, 256, 0, stream>>>(seq16, ltp, cap,
      ro_w1, ro_b1, ro_w2, ro_b2, ro_w3, ro_b3, out);
}

// Round 4
// 864.966 us; speedup vs baseline: 2.5472x; 1.0348x over previous
//
#include <hip/hip_runtime.h>
#include <math.h>

#define N_PATHS 50000
#define N_LINKS 10000
#define LPATH   8
#define DEG     40
#define DIM     64
#define G3      192
#define ITERS   8

typedef float f32x4  __attribute__((ext_vector_type(4)));
typedef short bf16x8 __attribute__((ext_vector_type(8)));

__device__ __forceinline__ float fsigmoid(float x){ return 1.0f/(1.0f + __expf(-x)); }
__device__ __forceinline__ float ftanh(float x){ return 1.0f - 2.0f/(__expf(2.0f*x) + 1.0f); }
__device__ __forceinline__ unsigned short bf16_rne(float v){
  unsigned u = __float_as_uint(v);
  return (unsigned short)((u + 0x7FFFu + ((u>>16)&1u)) >> 16);
}
// split 8 fp32 into bf16 hi + bf16 residual (used only in link_fused)
__device__ __forceinline__ void split8(const float* s, bf16x8& hi, bf16x8& lo){
  #pragma unroll
  for (int e=0;e<8;e++){
    unsigned short hb = bf16_rne(s[e]);
    float lof = s[e] - __uint_as_float(((unsigned)hb)<<16);
    hi[e] = (short)hb; lo[e] = (short)bf16_rne(lof);
  }
}
__device__ __forceinline__ void accum8(float* a, uint4 v){
  unsigned x[4] = {v.x, v.y, v.z, v.w};
  #pragma unroll
  for (int q=0;q<4;q++){
    a[2*q]   += __uint_as_float((x[q]&0xFFFFu)<<16);
    a[2*q+1] += __uint_as_float(x[q]&0xFFFF0000u);
  }
}

// ---------------- path embedding ----------------
__global__ __launch_bounds__(256) void path_embed(
    const float* __restrict__ ft, const float* __restrict__ fp, const float* __restrict__ fps,
    const float* __restrict__ w1, const float* __restrict__ b1,
    const float* __restrict__ w2, const float* __restrict__ b2,
    float* __restrict__ path_state)
{
  __shared__ float h1[4][DIM];
  int j  = threadIdx.x & 63;
  int pl = threadIdx.x >> 6;
  int p  = blockIdx.x*4 + pl;
  float x0 = ft[p]*1e-4f, x1 = fp[p]*1e-3f, x2 = fps[p]*1e-3f;
  float h = b1[j] + x0*w1[0*DIM+j] + x1*w1[1*DIM+j] + x2*w1[2*DIM+j];
  h1[pl][j] = fmaxf(h, 0.f);
  __syncthreads();
  float acc = b2[j];
  #pragma unroll 8
  for (int k=0;k<DIM;k++) acc = fmaf(h1[pl][k], w2[k*DIM+j], acc);
  path_state[p*DIM+j] = fmaxf(acc, 0.f);
}

// ---------------- link embedding ----------------
__global__ __launch_bounds__(256) void link_embed(
    const float* __restrict__ ft, const float* __restrict__ cap, const int* __restrict__ ptl,
    const float* __restrict__ w1, const float* __restrict__ b1,
    const float* __restrict__ w2, const float* __restrict__ b2,
    float* __restrict__ link_state)
{
  __shared__ float h1[4][DIM];
  int j  = threadIdx.x & 63;
  int wl = threadIdx.x >> 6;
  int l  = blockIdx.x*4 + wl;
  float s = 0.f;
  if (j < DEG) s = ft[ptl[(l*DEG + j)*2 + 0]];
  #pragma unroll
  for (int off=32; off; off>>=1) s += __shfl_down(s, off);
  float load = __shfl(s, 0) / (cap[l]*1e9f);
  float x0 = cap[l]*1e-5f;
  float h = b1[j] + x0*w1[0*DIM+j] + load*w1[1*DIM+j];
  h1[wl][j] = fmaxf(h, 0.f);
  __syncthreads();
  float acc = b2[j];
  #pragma unroll 8
  for (int k=0;k<DIM;k++) acc = fmaf(h1[wl][k], w2[k*DIM+j], acc);
  link_state[l*DIM+j] = fmaxf(acc, 0.f);
}

// ---------------- pack 4 weight mats into bf16 MFMA B-fragments ----------------
// m: 0=pg_wh, 1=pg_wx, 2=lg_wx, 3=lg_wh. frag f=nt*2+kc.
// elem i of lane l = w[kc*32+(l>>4)*8+i][nt*16+(l&15)], at whf[((m*24+f)*512) + l*8 + i]
__global__ __launch_bounds__(256) void pack_frags(
    const float* __restrict__ pg_wh, const float* __restrict__ pg_wx,
    const float* __restrict__ lg_wx, const float* __restrict__ lg_wh,
    unsigned short* __restrict__ whf)
{
  int tid = blockIdx.x*256 + threadIdx.x;
  if (tid >= 4*24*512) return;
  int i = tid & 7, l = (tid>>3)&63, f = (tid>>9)%24, m = tid/(24*512);
  int nt = f>>1, kc = f&1;
  int k = kc*32 + (l>>4)*8 + i;
  int n = nt*16 + (l&15);
  const float* src = (m==0)?pg_wh : (m==1)?pg_wx : (m==2)?lg_wx : lg_wh;
  whf[tid] = bf16_rne(src[k*G3 + n]);
}

// ---------------- initial LX = link_state @ pg_wx + pg_bx (+pg_bh z,r fold) ----------------
__global__ __launch_bounds__(192) void compute_lx(
    const float* __restrict__ link_state, const float* __restrict__ wx,
    const float* __restrict__ bx, const float* __restrict__ bh, float* __restrict__ LX)
{
  __shared__ float ls[4][DIM];
  int g  = threadIdx.x;
  int l0 = blockIdx.x*4;
  if (g < DIM){
    #pragma unroll
    for (int li=0; li<4; li++) ls[li][g] = link_state[(l0+li)*DIM+g];
  }
  __syncthreads();
  float b = bx[g] + (g < 128 ? bh[g] : 0.f);
  float a0=b, a1=b, a2=b, a3=b;
  #pragma unroll 8
  for (int k=0;k<DIM;k++){
    float w = wx[k*G3+g];
    a0 = fmaf(ls[0][k], w, a0);
    a1 = fmaf(ls[1][k], w, a1);
    a2 = fmaf(ls[2][k], w, a2);
    a3 = fmaf(ls[3][k], w, a3);
  }
  LX[(l0+0)*G3+g]=a0; LX[(l0+1)*G3+g]=a1; LX[(l0+2)*G3+g]=a2; LX[(l0+3)*G3+g]=a3;
}

// ---------------- MFMA 8-step GRU scan. wave = 16 paths, bf16 h in LDS, weights in LDS ----------------
__global__ __launch_bounds__(256) void path_scan_mfma(
    const float* __restrict__ LX, const int* __restrict__ ltp,
    const unsigned short* __restrict__ whf, const float* __restrict__ bh,
    float* __restrict__ path_state, unsigned short* __restrict__ seq16)
{
  __shared__ __align__(16) unsigned short bw_lds[24*512];   // 24.5 KB B-fragments
  __shared__ __align__(16) unsigned short htile[4][16*72];  // 9.2 KB, h as bf16, pitch 72
  __shared__ int ltps[4][128];                              // 2 KB
  int tid = threadIdx.x, l = tid & 63, w = tid >> 6;
  int lg = l >> 4, lr = l & 15;
  int p0 = blockIdx.x*64 + w*16;
  if (p0 > N_PATHS-16) p0 = N_PATHS-16;   // clamp: duplicate waves write identical data

  // cooperative weight stage: 24576 B = 256 threads x 6 uint4
  {
    const uint4* src = (const uint4*)whf;
    uint4* dst = (uint4*)bw_lds;
    #pragma unroll
    for (int i=0;i<6;i++) dst[i*256+tid] = src[i*256+tid];
  }

  float bhq[4];
  #pragma unroll
  for (int q=0;q<4;q++) bhq[q] = bh[128 + q*16 + lr];

  *(int2*)&ltps[w][l*2] = *(const int2*)(ltp + (size_t)p0*LPATH + l*2);

  // stage initial h as bf16 into htile (coalesced float4 global reads)
  #pragma unroll
  for (int rep=0; rep<4; rep++){
    int idx = rep*64 + l;
    int pi = idx >> 4, c4 = (idx & 15)*4;
    float4 v = *(const float4*)(path_state + (size_t)(p0+pi)*DIM + c4);
    unsigned short* dst = &htile[w][pi*72 + c4];
    dst[0]=bf16_rne(v.x); dst[1]=bf16_rne(v.y); dst[2]=bf16_rne(v.z); dst[3]=bf16_rne(v.w);
  }
  // fp32 h_old in registers (D-fragment layout) keeps the blend exact
  f32x4 hold[4];
  #pragma unroll
  for (int nt=0;nt<4;nt++){
    #pragma unroll
    for (int r=0;r<4;r++)
      hold[nt][r] = path_state[(size_t)(p0+lg*4+r)*DIM + nt*16 + lr];
  }

  __syncthreads();   // weights visible; htile/ltps are wave-private

  for (int t=0; t<LPATH; t++){
    f32x4 acc[12]; f32x4 xq[4];
    #pragma unroll
    for (int r=0;r<4;r++){
      int lk = ltps[w][(lg*4+r)*LPATH + t];
      const float* lxr = LX + (size_t)lk*G3;
      #pragma unroll
      for (int nt=0;nt<8;nt++) acc[nt][r] = lxr[nt*16+lr];
      #pragma unroll
      for (int q=0;q<4;q++){ xq[q][r] = lxr[128+q*16+lr]; acc[8+q][r] = bhq[q]; }
    }
    // A-fragments straight from bf16 htile (no split)
    bf16x8 a0 = *(const bf16x8*)&htile[w][lr*72 +  0 + lg*8];
    bf16x8 a1 = *(const bf16x8*)&htile[w][lr*72 + 32 + lg*8];
    #pragma unroll
    for (int nt=0;nt<12;nt++){
      bf16x8 b0 = *(const bf16x8*)&bw_lds[(nt*2+0)*512 + l*8];
      acc[nt] = __builtin_amdgcn_mfma_f32_16x16x32_bf16(a0, b0, acc[nt], 0,0,0);
      bf16x8 b1 = *(const bf16x8*)&bw_lds[(nt*2+1)*512 + l*8];
      acc[nt] = __builtin_amdgcn_mfma_f32_16x16x32_bf16(a1, b1, acc[nt], 0,0,0);
    }
    // gates + blend, write bf16 h to htile + seq
    #pragma unroll
    for (int nt=0;nt<4;nt++){
      #pragma unroll
      for (int r=0;r<4;r++){
        float z  = fsigmoid(acc[nt][r]);
        float rr = fsigmoid(acc[4+nt][r]);
        float hh = ftanh(xq[nt][r] + rr*acc[8+nt][r]);
        float hn = z*hold[nt][r] + (1.f-z)*hh;
        hold[nt][r] = hn;
        unsigned short u = bf16_rne(hn);
        htile[w][(lg*4+r)*72 + nt*16 + lr] = u;
        seq16[((size_t)(p0+lg*4+r)*LPATH + t)*DIM + nt*16 + lr] = u;
      }
    }
  }
  #pragma unroll
  for (int nt=0;nt<4;nt++){
    #pragma unroll
    for (int r=0;r<4;r++)
      path_state[(size_t)(p0+lg*4+r)*DIM + nt*16 + lr] = hold[nt][r];
  }
}

// ---------------- fused link update: 4-wave cooperative gather -> GRU (MFMA) -> next LX ----------------
// block = 256 threads (4 waves), 16 links; each wave sums 10 of 40 DEG entries
__global__ __launch_bounds__(256) void link_fused(
    const unsigned short* __restrict__ seq16, const int* __restrict__ ptl,
    const unsigned short* __restrict__ whf,
    const float* __restrict__ lbx, const float* __restrict__ lbh,
    const float* __restrict__ pbx, const float* __restrict__ pbh,
    float* __restrict__ link_state, float* __restrict__ LX)
{
  __shared__ float pspart[4][16][64];   // [wave][elem][lane] - conflict-free scalar access
  __shared__ float tile[16*68];
  int tid = threadIdx.x, l = tid & 63, w = tid >> 6;
  int lr = l & 15, lg = l >> 4;
  int l0 = blockIdx.x*16;

  float ps[16];
  #pragma unroll
  for (int i=0;i<16;i++) ps[i]=0.f;
  {
    const int* pe = ptl + (size_t)(l0+lr)*DEG*2 + w*10*2;
    #pragma unroll
    for (int d=0; d<10; d++){
      int pp = pe[2*d], tt = pe[2*d+1];
      const unsigned short* rowp = seq16 + ((size_t)pp*LPATH + (tt-1))*DIM;
      accum8(ps,   *(const uint4*)(rowp + lg*8));
      accum8(ps+8, *(const uint4*)(rowp + 32 + lg*8));
    }
  }
  #pragma unroll
  for (int i=0;i<16;i++) pspart[w][i][l] = ps[i];
  __syncthreads();
  if (w != 0) return;     // wave 0 finishes alone; no further barriers

  #pragma unroll
  for (int i=0;i<16;i++)
    ps[i] = pspart[0][i][l] + pspart[1][i][l] + pspart[2][i][l] + pspart[3][i][l];

  // mx = psum @ lg_wx + lbx ; mh = ls @ lg_wh + lbh  (hi/lo split kept: ps is large-magnitude)
  f32x4 mxa[12], mha[12];
  #pragma unroll
  for (int nt=0;nt<12;nt++){
    float bxv = lbx[nt*16+lr], bhv = lbh[nt*16+lr];
    mxa[nt] = (f32x4){bxv,bxv,bxv,bxv};
    mha[nt] = (f32x4){bhv,bhv,bhv,bhv};
  }
  #pragma unroll
  for (int kc=0;kc<2;kc++){
    bf16x8 phi, plo; split8(ps + kc*8, phi, plo);
    float hs[8];
    const float* lsr = link_state + (size_t)(l0+lr)*DIM + kc*32 + lg*8;
    *(f32x4*)hs = *(const f32x4*)lsr;
    *(f32x4*)(hs+4) = *(const f32x4*)(lsr+4);
    bf16x8 lhi, llo; split8(hs, lhi, llo);
    #pragma unroll
    for (int nt=0;nt<12;nt++){
      bf16x8 bwx = *(const bf16x8*)(whf + (size_t)((2*24 + nt*2+kc)*512) + l*8);
      mxa[nt] = __builtin_amdgcn_mfma_f32_16x16x32_bf16(phi, bwx, mxa[nt], 0,0,0);
      mxa[nt] = __builtin_amdgcn_mfma_f32_16x16x32_bf16(plo, bwx, mxa[nt], 0,0,0);
      bf16x8 bwh = *(const bf16x8*)(whf + (size_t)((3*24 + nt*2+kc)*512) + l*8);
      mha[nt] = __builtin_amdgcn_mfma_f32_16x16x32_bf16(lhi, bwh, mha[nt], 0,0,0);
      mha[nt] = __builtin_amdgcn_mfma_f32_16x16x32_bf16(llo, bwh, mha[nt], 0,0,0);
    }
  }

  #pragma unroll
  for (int nt=0;nt<4;nt++){
    #pragma unroll
    for (int r=0;r<4;r++){
      size_t lk = (size_t)(l0 + lg*4 + r)*DIM + nt*16 + lr;
      float lsv = link_state[lk];
      float z  = fsigmoid(mxa[nt][r] + mha[nt][r]);
      float rr = fsigmoid(mxa[4+nt][r] + mha[4+nt][r]);
      float hh = ftanh(mxa[8+nt][r] + rr*mha[8+nt][r]);
      float hn = z*lsv + (1.f-z)*hh;
      link_state[lk] = hn;
      tile[(lg*4+r)*68 + nt*16 + lr] = hn;
    }
  }

  // next-iteration LX = h' @ pg_wx + pg_bx (+pg_bh fold for z,r)
  f32x4 lxa[12];
  #pragma unroll
  for (int nt=0;nt<12;nt++){
    int g = nt*16 + lr;
    float b = pbx[g] + (g < 128 ? pbh[g] : 0.f);
    lxa[nt] = (f32x4){b,b,b,b};
  }
  #pragma unroll
  for (int kc=0;kc<2;kc++){
    float hs[8];
    #pragma unroll
    for (int i=0;i<8;i++) hs[i] = tile[lr*68 + kc*32 + lg*8 + i];
    bf16x8 hhi, hlo; split8(hs, hhi, hlo);
    #pragma unroll
    for (int nt=0;nt<12;nt++){
      bf16x8 bw = *(const bf16x8*)(whf + (size_t)((1*24 + nt*2+kc)*512) + l*8);
      lxa[nt] = __builtin_amdgcn_mfma_f32_16x16x32_bf16(hhi, bw, lxa[nt], 0,0,0);
      lxa[nt] = __builtin_amdgcn_mfma_f32_16x16x32_bf16(hlo, bw, lxa[nt], 0,0,0);
    }
  }
  #pragma unroll
  for (int nt=0;nt<12;nt++){
    #pragma unroll
    for (int r=0;r<4;r++)
      LX[(size_t)(l0 + lg*4 + r)*G3 + nt*16 + lr] = lxa[nt][r];
  }
}

// ---------------- readout: LDS-staged coalesced reads + MLP + delay reduce ----------------
__global__ __launch_bounds__(256) void readout(
    const unsigned short* __restrict__ seq16, const int* __restrict__ ltp,
    const float* __restrict__ cap,
    const float* __restrict__ w1, const float* __restrict__ b1,
    const float* __restrict__ w2, const float* __restrict__ b2,
    const float* __restrict__ w3, const float* __restrict__ b3,
    float* __restrict__ out)
{
  __shared__ unsigned short rows_sh[4][64*72];
  __shared__ float w1s[DIM*32];
  __shared__ float w2s[32*16];
  __shared__ float w3s[16];
  __shared__ float b1s[32], b2s[16];
  int tid = threadIdx.x;
  for (int i=tid;i<DIM*32;i+=256) w1s[i]=w1[i];
  for (int i=tid;i<32*16;i+=256) w2s[i]=w2[i];
  if (tid<16) w3s[tid]=w3[tid];
  if (tid<32) b1s[tid]=b1[tid];
  if (tid<16) b2s[tid]=b2[tid];
  __syncthreads();

  int l = tid & 63, w = tid >> 6;
  size_t wave_r = (size_t)blockIdx.x*256 + (size_t)w*64;
  if (wave_r >= (size_t)N_PATHS*LPATH) return;

  const unsigned short* src = seq16 + wave_r*DIM;
  #pragma unroll
  for (int i=0;i<16;i++){
    int e  = i*64 + l;
    int ri = e >> 4;
    int c4 = e & 15;
    *(uint2*)&rows_sh[w][ri*72 + c4*4] = *(const uint2*)(src + (size_t)e*4);
  }

  size_t row = wave_r + l;
  const unsigned short* myrow = &rows_sh[w][l*72];
  float a[32];
  #pragma unroll
  for (int j=0;j<32;j++) a[j]=b1s[j];
  #pragma unroll
  for (int c=0;c<16;c++){
    uint2 v = *(const uint2*)(myrow + c*4);
    float f0 = __uint_as_float((v.x & 0xFFFFu) << 16);
    float f1 = __uint_as_float(v.x & 0xFFFF0000u);
    float f2 = __uint_as_float((v.y & 0xFFFFu) << 16);
    float f3 = __uint_as_float(v.y & 0xFFFF0000u);
    #pragma unroll
    for (int j=0;j<32;j++) a[j] = fmaf(f0, w1s[(c*4+0)*32+j], a[j]);
    #pragma unroll
    for (int j=0;j<32;j++) a[j] = fmaf(f1, w1s[(c*4+1)*32+j], a[j]);
    #pragma unroll
    for (int j=0;j<32;j++) a[j] = fmaf(f2, w1s[(c*4+2)*32+j], a[j]);
    #pragma unroll
    for (int j=0;j<32;j++) a[j] = fmaf(f3, w1s[(c*4+3)*32+j], a[j]);
  }
  float h2[16];
  #pragma unroll
  for (int j2=0;j2<16;j2++) h2[j2]=b2s[j2];
  #pragma unroll
  for (int j=0;j<32;j++){
    float hv = fmaxf(a[j],0.f);
    #pragma unroll
    for (int j2=0;j2<16;j2++) h2[j2] = fmaf(hv, w2s[j*16+j2], h2[j2]);
  }
  float o = b3[0];
  #pragma unroll
  for (int j2=0;j2<16;j2++) o = fmaf(fmaxf(h2[j2],0.f), w3s[j2], o);
  float sp = (o > 20.f) ? o : log1pf(__expf(o));
  float dly = sp / cap[ltp[row]];
  dly += __shfl_xor(dly, 1);
  dly += __shfl_xor(dly, 2);
  dly += __shfl_xor(dly, 4);
  if ((l & 7) == 0) out[row >> 3] = dly;
}

extern "C" void kernel_launch(void* const* d_in, const int* in_sizes, int n_in,
                              void* d_out, int out_size, void* d_ws, size_t ws_size,
                              hipStream_t stream) {
  const float* ft    = (const float*)d_in[0];
  const float* fpk   = (const float*)d_in[1];
  const float* fps   = (const float*)d_in[2];
  const float* cap   = (const float*)d_in[3];
  const int*   ltp   = (const int*)  d_in[4];
  const int*   ptl   = (const int*)  d_in[5];
  const float* pe_w1 = (const float*)d_in[6];
  const float* pe_b1 = (const float*)d_in[7];
  const float* pe_w2 = (const float*)d_in[8];
  const float* pe_b2 = (const float*)d_in[9];
  const float* le_w1 = (const float*)d_in[10];
  const float* le_b1 = (const float*)d_in[11];
  const float* le_w2 = (const float*)d_in[12];
  const float* le_b2 = (const float*)d_in[13];
  const float* pg_wx = (const float*)d_in[14];
  const float* pg_wh = (const float*)d_in[15];
  const float* pg_bx = (const float*)d_in[16];
  const float* pg_bh = (const float*)d_in[17];
  const float* lg_wx = (const float*)d_in[18];
  const float* lg_wh = (const float*)d_in[19];
  const float* lg_bx = (const float*)d_in[20];
  const float* lg_bh = (const float*)d_in[21];
  const float* ro_w1 = (const float*)d_in[22];
  const float* ro_b1 = (const float*)d_in[23];
  const float* ro_w2 = (const float*)d_in[24];
  const float* ro_b2 = (const float*)d_in[25];
  const float* ro_w3 = (const float*)d_in[26];
  const float* ro_b3 = (const float*)d_in[27];
  float* out = (float*)d_out;

  float* path_state = (float*)d_ws;
  float* link_state = path_state + (size_t)N_PATHS*DIM;
  float* LXf        = link_state + (size_t)N_LINKS*DIM;
  unsigned short* seq16 = (unsigned short*)(LXf + (size_t)N_LINKS*G3);
  unsigned short* whf   = seq16 + (size_t)N_PATHS*LPATH*DIM;

  path_embed<<<N_PATHS/4, 256, 0, stream>>>(ft, fpk, fps, pe_w1, pe_b1, pe_w2, pe_b2, path_state);
  link_embed<<<N_LINKS/4, 256, 0, stream>>>(ft, cap, ptl, le_w1, le_b1, le_w2, le_b2, link_state);
  pack_frags<<<192, 256, 0, stream>>>(pg_wh, pg_wx, lg_wx, lg_wh, whf);
  compute_lx<<<N_LINKS/4, 192, 0, stream>>>(link_state, pg_wx, pg_bx, pg_bh, LXf);
  for (int it=0; it<ITERS; ++it){
    path_scan_mfma<<<(N_PATHS+63)/64, 256, 0, stream>>>(LXf, ltp, whf, pg_bh, path_state, seq16);
    if (it < ITERS-1)
      link_fused<<<N_LINKS/16, 256, 0, stream>>>(seq16, ptl, whf,
          lg_bx, lg_bh, pg_bx, pg_bh, link_state, LXf);
  }
  readout<<<(N_PATHS*LPATH + 255)/256, 256, 0, stream>>>(seq16, ltp, cap,
      ro_w1, ro_b1, ro_w2, ro_b2, ro_w3, ro_b3, out);
}